// Round 9
// baseline (473.498 us; speedup 1.0000x reference)
//
#include <hip/hip_runtime.h>

// SSIM loss, fused single-pass — NO-LDS, NO-RING, 4-cols/thread float4 version.
// R8 post-mortem: spill fixed (WRITE 32B, VGPR 56) but latency-bound remained:
// occupancy 36.65% (1024 blocks = 4/CU), VALUBusy 28.7%, 10 float2 loads/hacc.
// Fix: thread owns 4 cols -> 3 float4 loads per image per row (1.5 loads/px vs 5),
// BAND=8 with 2 row-bands per block -> 2048 blocks = 8 blocks/CU = up to 32
// waves/CU. Sliding-window col sums keep per-px VALU flat. Still no ring:
// outgoing row recomputed (bit-identical, L2/L3-served).

constexpr int IMG = 512;
constexpr int BAND = 8;                // output rows per thread
constexpr float C1 = 1.0e-4f;          // 0.01^2
constexpr float C2 = 9.0e-4f;          // 0.03^2
constexpr double INV_N = 1.0 / (64.0 * 512.0 * 512.0);

__global__ __launch_bounds__(256, 4)
void ssim_fused(const float* __restrict__ img1, const float* __restrict__ img2,
                double* __restrict__ partial) {
    __shared__ float wpart[4];

    const int tid = threadIdx.x;
    const int cid = tid & 127;           // col-group id: cols 4*cid .. 4*cid+3
    const int band = tid >> 7;           // 0/1: which 8-row band in this block
    const int y0 = blockIdx.x * (2 * BAND) + band * BAND;
    const size_t ib = (size_t)blockIdx.y * (IMG * IMG);
    const float* b1 = img1 + ib;
    const float* b2 = img2 + ib;

    // window union for cols xb..xb+3 = floats [xb-3 .. xb+6] -> 3 float4 chunks
    const int xb = 4 * cid;
    const int xom = max(xb - 4, 0);      // clamped left chunk (stays in row)
    const int xop = min(xb + 4, IMG - 4);
    const bool pm = xb > 0;              // left chunk valid?
    const bool pp = (xb + 4) < IMG;      // right chunk valid?

    // vertical running 7-row sums: 5 quantities x 4 cols (static indices only)
    float SA[4], SB[4], SAA[4], SBB[4], SAB[4];
#pragma unroll
    for (int j = 0; j < 4; ++j) { SA[j] = SB[j] = SAA[j] = SBB[j] = SAB[j] = 0.f; }
    float acc = 0.f;

    // horizontal 7-tap sums of image row `row` for 4 cols, accumulated into S*
    // with sign sgn (+1 incoming, -1 outgoing). OOB rows: no contribution.
    auto hacc = [&](int row, float sgn) {
        if ((unsigned)row < (unsigned)IMG) {           // wave-uniform branch
            const float4 zz = make_float4(0.f, 0.f, 0.f, 0.f);
            const float* r1 = b1 + row * IMG;
            const float* r2 = b2 + row * IMG;
            float4 am = *(const float4*)(r1 + xom);
            float4 a0 = *(const float4*)(r1 + xb);
            float4 ap = *(const float4*)(r1 + xop);
            float4 cm = *(const float4*)(r2 + xom);
            float4 c0 = *(const float4*)(r2 + xb);
            float4 cp = *(const float4*)(r2 + xop);
            am = pm ? am : zz;  cm = pm ? cm : zz;     // zero-pad x edges
            ap = pp ? ap : zz;  cp = pp ? cp : zz;
            // w[i] = image value at col xb-4+i ; windows use w[1..10]
            float wa[12] = {am.x, am.y, am.z, am.w, a0.x, a0.y, a0.z, a0.w,
                            ap.x, ap.y, ap.z, ap.w};
            float wb[12] = {cm.x, cm.y, cm.z, cm.w, c0.x, c0.y, c0.z, c0.w,
                            cp.x, cp.y, cp.z, cp.w};

            {   // A
                float s = ((wa[1] + wa[2]) + (wa[3] + wa[4])) + ((wa[5] + wa[6]) + wa[7]);
                SA[0] = fmaf(sgn, s, SA[0]);
                s = (s - wa[1]) + wa[8];   SA[1] = fmaf(sgn, s, SA[1]);
                s = (s - wa[2]) + wa[9];   SA[2] = fmaf(sgn, s, SA[2]);
                s = (s - wa[3]) + wa[10];  SA[3] = fmaf(sgn, s, SA[3]);
            }
            {   // B
                float s = ((wb[1] + wb[2]) + (wb[3] + wb[4])) + ((wb[5] + wb[6]) + wb[7]);
                SB[0] = fmaf(sgn, s, SB[0]);
                s = (s - wb[1]) + wb[8];   SB[1] = fmaf(sgn, s, SB[1]);
                s = (s - wb[2]) + wb[9];   SB[2] = fmaf(sgn, s, SB[2]);
                s = (s - wb[3]) + wb[10];  SB[3] = fmaf(sgn, s, SB[3]);
            }
            {   // AA
                float q[11];
#pragma unroll
                for (int i = 1; i <= 10; ++i) q[i] = wa[i] * wa[i];
                float s = ((q[1] + q[2]) + (q[3] + q[4])) + ((q[5] + q[6]) + q[7]);
                SAA[0] = fmaf(sgn, s, SAA[0]);
                s = (s - q[1]) + q[8];    SAA[1] = fmaf(sgn, s, SAA[1]);
                s = (s - q[2]) + q[9];    SAA[2] = fmaf(sgn, s, SAA[2]);
                s = (s - q[3]) + q[10];   SAA[3] = fmaf(sgn, s, SAA[3]);
            }
            {   // BB
                float q[11];
#pragma unroll
                for (int i = 1; i <= 10; ++i) q[i] = wb[i] * wb[i];
                float s = ((q[1] + q[2]) + (q[3] + q[4])) + ((q[5] + q[6]) + q[7]);
                SBB[0] = fmaf(sgn, s, SBB[0]);
                s = (s - q[1]) + q[8];    SBB[1] = fmaf(sgn, s, SBB[1]);
                s = (s - q[2]) + q[9];    SBB[2] = fmaf(sgn, s, SBB[2]);
                s = (s - q[3]) + q[10];   SBB[3] = fmaf(sgn, s, SBB[3]);
            }
            {   // AB
                float q[11];
#pragma unroll
                for (int i = 1; i <= 10; ++i) q[i] = wa[i] * wb[i];
                float s = ((q[1] + q[2]) + (q[3] + q[4])) + ((q[5] + q[6]) + q[7]);
                SAB[0] = fmaf(sgn, s, SAB[0]);
                s = (s - q[1]) + q[8];    SAB[1] = fmaf(sgn, s, SAB[1]);
                s = (s - q[2]) + q[9];    SAB[2] = fmaf(sgn, s, SAB[2]);
                s = (s - q[3]) + q[10];   SAB[3] = fmaf(sgn, s, SAB[3]);
            }
        }
    };

    // prime: window rows y0-3 .. y0+2
#pragma unroll
    for (int k = -3; k < 3; ++k) hacc(y0 + k, 1.f);

    // BAND output rows
#pragma unroll 2
    for (int t = 0; t < BAND; ++t) {
        hacc(y0 + t + 3, 1.f);     // incoming window row

#pragma unroll
        for (int j = 0; j < 4; ++j) {
            float m12 = SA[j] * SB[j], m11 = SA[j] * SA[j], m22 = SB[j] * SB[j];
            float num = fmaf(2.f, m12, C1) * fmaf(2.f, SAB[j] - m12, C2);
            float den = (m11 + m22 + C1) * ((SAA[j] - m11) + (SBB[j] - m22) + C2);
            acc = fmaf(num, __builtin_amdgcn_rcpf(den), acc);
        }

        hacc(y0 + t - 3, -1.f);    // outgoing window row, recomputed (cache-served)
    }

    // ---- reduce: wave shuffle -> LDS -> one double atomic per block ----
#pragma unroll
    for (int off = 32; off > 0; off >>= 1)
        acc += __shfl_xor(acc, off);
    if ((tid & 63) == 0) wpart[tid >> 6] = acc;
    __syncthreads();
    if (tid == 0)
        atomicAdd(partial, (double)((wpart[0] + wpart[1]) + (wpart[2] + wpart[3])));
}

__global__ void ssim_finalize(const double* __restrict__ partial,
                              float* __restrict__ out) {
    out[0] = (float)(1.0 - partial[0] * INV_N);
}

extern "C" void kernel_launch(void* const* d_in, const int* in_sizes, int n_in,
                              void* d_out, int out_size, void* d_ws, size_t ws_size,
                              hipStream_t stream) {
    const float* img1 = (const float*)d_in[0];
    const float* img2 = (const float*)d_in[1];
    float* out = (float*)d_out;
    double* partial = (double*)d_ws;

    hipMemsetAsync(partial, 0, sizeof(double), stream);

    dim3 grid(IMG / (2 * BAND), 64);   // 32 x 64 = 2048 blocks, 8/CU
    ssim_fused<<<grid, 256, 0, stream>>>(img1, img2, partial);
    ssim_finalize<<<1, 1, 0, stream>>>(partial, out);
}

// Round 13
// 232.536 us; speedup vs baseline: 2.0362x; 2.0362x over previous
//
#include <hip/hip_runtime.h>

// SSIM loss, fused single-pass — NO-LDS, NO-RING (R8 structure, BAND 32->16).
// R9 post-mortem: (256,4) re-capped regs at 128 and re-spilled the 4-col hacc
// (WRITE 452 MB) — law confirmed 3x: this family needs (256,<=3).
// R8 re-read: occupancy 36.65% was GRID-limited (1024 blocks x 4 waves = 4096
// waves vs 8192 slots = 50% ceiling), not latency. Fix: BAND=16 -> 2048 blocks
// -> 100% potential occupancy. Everything else identical to R8 (VGPR 56,
// WRITE 32 B, zero bank conflicts).

constexpr int IMG = 512;
constexpr int BAND = 16;               // output rows per block (grid 32x64)
constexpr float C1 = 1.0e-4f;          // 0.01^2
constexpr float C2 = 9.0e-4f;          // 0.03^2
constexpr double INV_N = 1.0 / (64.0 * 512.0 * 512.0);

__global__ __launch_bounds__(256, 3)
void ssim_fused(const float* __restrict__ img1, const float* __restrict__ img2,
                double* __restrict__ partial) {
    __shared__ float wpart[4];

    const int tid = threadIdx.x;
    const int y0 = blockIdx.x * BAND;
    const size_t ib = (size_t)blockIdx.y * (IMG * IMG);
    const float* b1 = img1 + ib;
    const float* b2 = img2 + ib;

    // thread owns cols (2c, 2c+1); window union = floats [2c-4 .. 2c+5]
    const int xb = 2 * tid;
    const int xo0 = max(xb - 4, 0);          // clamped chunk offsets (stay in-row)
    const int xo1 = max(xb - 2, 0);
    const int xo2 = xb;
    const int xo3 = min(xb + 2, IMG - 2);
    const int xo4 = min(xb + 4, IMG - 2);
    const bool p0 = (xb - 4) >= 0;           // chunk-valid predicates
    const bool p1 = (xb - 2) >= 0;
    const bool p3 = (xb + 2) < IMG;
    const bool p4 = (xb + 4) < IMG;

    // vertical running 7-row sums, 5 quantities x 2 columns — the ONLY state
    float SA0 = 0, SA1 = 0, SB0 = 0, SB1 = 0, SAA0 = 0, SAA1 = 0,
          SBB0 = 0, SBB1 = 0, SAB0 = 0, SAB1 = 0;
    float acc = 0.f;

    // horizontal 7-tap sums of image row `row`, accumulated into S* with sign
    // sgn (+1 incoming, -1 outgoing). OOB rows contribute nothing (zero pad).
    auto hacc = [&](int row, float sgn) {
        if ((unsigned)row < (unsigned)IMG) {             // wave-uniform branch
            const float2 zz = make_float2(0.f, 0.f);
            const float* r1 = b1 + row * IMG;
            const float* r2 = b2 + row * IMG;
            float2 a0 = *(const float2*)(r1 + xo0);
            float2 a1 = *(const float2*)(r1 + xo1);
            float2 a2 = *(const float2*)(r1 + xo2);
            float2 a3 = *(const float2*)(r1 + xo3);
            float2 a4 = *(const float2*)(r1 + xo4);
            float2 c0 = *(const float2*)(r2 + xo0);
            float2 c1v = *(const float2*)(r2 + xo1);
            float2 c2v = *(const float2*)(r2 + xo2);
            float2 c3 = *(const float2*)(r2 + xo3);
            float2 c4 = *(const float2*)(r2 + xo4);
            a0 = p0 ? a0 : zz;  c0 = p0 ? c0 : zz;       // zero-pad x edges
            a1 = p1 ? a1 : zz;  c1v = p1 ? c1v : zz;
            a3 = p3 ? a3 : zz;  c3 = p3 ? c3 : zz;
            a4 = p4 ? a4 : zz;  c4 = p4 ? c4 : zz;

            float va1 = a0.y, va2 = a1.x, va3 = a1.y, va4 = a2.x,
                  va5 = a2.y, va6 = a3.x, va7 = a3.y, va8 = a4.x;
            float vb1 = c0.y, vb2 = c1v.x, vb3 = c1v.y, vb4 = c2v.x,
                  vb5 = c2v.y, vb6 = c3.x, vb7 = c3.y, vb8 = c4.x;

            float sA = ((va1 + va2) + (va3 + va4)) + ((va5 + va6) + va7);
            SA0 = fmaf(sgn, sA, SA0);
            SA1 = fmaf(sgn, (sA - va1) + va8, SA1);

            float sB = ((vb1 + vb2) + (vb3 + vb4)) + ((vb5 + vb6) + vb7);
            SB0 = fmaf(sgn, sB, SB0);
            SB1 = fmaf(sgn, (sB - vb1) + vb8, SB1);

            float q1 = va1 * va1;
            float sAA = fmaf(va7, va7, fmaf(va6, va6, fmaf(va5, va5,
                        fmaf(va4, va4, fmaf(va3, va3, fmaf(va2, va2, q1))))));
            SAA0 = fmaf(sgn, sAA, SAA0);
            SAA1 = fmaf(sgn, fmaf(va8, va8, sAA - q1), SAA1);

            float q2 = vb1 * vb1;
            float sBB = fmaf(vb7, vb7, fmaf(vb6, vb6, fmaf(vb5, vb5,
                        fmaf(vb4, vb4, fmaf(vb3, vb3, fmaf(vb2, vb2, q2))))));
            SBB0 = fmaf(sgn, sBB, SBB0);
            SBB1 = fmaf(sgn, fmaf(vb8, vb8, sBB - q2), SBB1);

            float q3 = va1 * vb1;
            float sAB = fmaf(va7, vb7, fmaf(va6, vb6, fmaf(va5, vb5,
                        fmaf(va4, vb4, fmaf(va3, vb3, fmaf(va2, vb2, q3))))));
            SAB0 = fmaf(sgn, sAB, SAB0);
            SAB1 = fmaf(sgn, fmaf(va8, vb8, sAB - q3), SAB1);
        }
    };

    // prime: window rows y0-3 .. y0+2
#pragma unroll
    for (int k = -3; k < 3; ++k) hacc(y0 + k, 1.f);

    // BAND output rows; moderate unroll — no ring, so no static-index need
#pragma unroll 4
    for (int t = 0; t < BAND; ++t) {
        hacc(y0 + t + 3, 1.f);    // incoming window row

        {   // SSIM, col 2c
            float m12 = SA0 * SB0, m11 = SA0 * SA0, m22 = SB0 * SB0;
            float num = fmaf(2.f, m12, C1) * fmaf(2.f, SAB0 - m12, C2);
            float den = (m11 + m22 + C1) * ((SAA0 - m11) + (SBB0 - m22) + C2);
            acc = fmaf(num, __builtin_amdgcn_rcpf(den), acc);
        }
        {   // SSIM, col 2c+1
            float m12 = SA1 * SB1, m11 = SA1 * SA1, m22 = SB1 * SB1;
            float num = fmaf(2.f, m12, C1) * fmaf(2.f, SAB1 - m12, C2);
            float den = (m11 + m22 + C1) * ((SAA1 - m11) + (SBB1 - m22) + C2);
            acc = fmaf(num, __builtin_amdgcn_rcpf(den), acc);
        }

        hacc(y0 + t - 3, -1.f);   // outgoing window row, recomputed (cache hit)
    }

    // ---- reduce: wave shuffle -> LDS -> one double atomic per block ----
#pragma unroll
    for (int off = 32; off > 0; off >>= 1)
        acc += __shfl_xor(acc, off);
    if ((tid & 63) == 0) wpart[tid >> 6] = acc;
    __syncthreads();
    if (tid == 0)
        atomicAdd(partial, (double)((wpart[0] + wpart[1]) + (wpart[2] + wpart[3])));
}

__global__ void ssim_finalize(const double* __restrict__ partial,
                              float* __restrict__ out) {
    out[0] = (float)(1.0 - partial[0] * INV_N);
}

extern "C" void kernel_launch(void* const* d_in, const int* in_sizes, int n_in,
                              void* d_out, int out_size, void* d_ws, size_t ws_size,
                              hipStream_t stream) {
    const float* img1 = (const float*)d_in[0];
    const float* img2 = (const float*)d_in[1];
    float* out = (float*)d_out;
    double* partial = (double*)d_ws;

    hipMemsetAsync(partial, 0, sizeof(double), stream);

    dim3 grid(IMG / BAND, 64);    // 32 bands x 64 images = 2048 blocks
    ssim_fused<<<grid, 256, 0, stream>>>(img1, img2, partial);
    ssim_finalize<<<1, 1, 0, stream>>>(partial, out);
}